// Round 1
// 543.271 us; speedup vs baseline: 1.2386x; 1.2386x over previous
//
#include <hip/hip_runtime.h>
#include <stdint.h>

// ---------------------------------------------------------------------------
// HetAgg on MI355X.  D=128, T=10, L=2, B=4096; ND=20000/FD=2048,
// NG=20000/FG=1024, NC=10000/FC=512.
//
// v5: launch-merge pass. 23 dispatches -> 8:
//   - one proj launch (grid (625,3), struct args) instead of 3
//   - one xw launch (grid (640,3,6)) instead of 6
//   - one scan launch (grid (256,6) = 1536 blocks -> 2 blocks/CU instead of
//     1 block/CU; the scan was pure exposed-latency at 1 wave/SIMD)
//   - weight prep 5 -> 2 launches
// All 6 (l,t) GRU chains are mutually independent (cands never depend on h),
// so they merge safely. Requires 6-slot xwb (189 MB) + 6-slot cand; host
// checks ws_size and falls back to the old sequential path if too small.
// Drug projection now also stores bf16 so xw gathers 2 B/elem everywhere.
//
// MFMA 16x16x32 bf16 layouts (HW-verified):
//   A: A[m=lane&15][k=quad*8+j]  B: B[k=quad*8+j][n=lane&15]
//   C/D: row=quad*4+reg, col=lane&15
// ---------------------------------------------------------------------------

typedef short bf16x8 __attribute__((ext_vector_type(8)));
typedef float f32x4  __attribute__((ext_vector_type(4)));

__device__ __forceinline__ short f2bf(float f) {
  union { float f; unsigned u; } v; v.f = f;
  unsigned r = (v.u + 0x7fffu + ((v.u >> 16) & 1u)) >> 16;   // RNE
  return (short)r;
}
__device__ __forceinline__ float b2f(short s) {
  union { float f; unsigned u; } v; v.u = ((unsigned)(unsigned short)s) << 16;
  return v.f;
}
__device__ __forceinline__ f32x4 mfma_bf16(bf16x8 a, bf16x8 b, f32x4 c) {
  return __builtin_amdgcn_mfma_f32_16x16x32_bf16(a, b, c, 0, 0, 0);
}

// ---------------------------------------------------------------------------
// weight prep: three input-proj weights in one launch.
// src f32 [K][128] -> dst bf16 [128][K]
struct PrepW { const float* src[3]; short* dst[3]; int K[3]; };

__global__ __launch_bounds__(256) void prep_w(PrepW a) {
  const int y = blockIdx.y;
  const int K = a.K[y];
  int i = blockIdx.x * 256 + threadIdx.x;
  if (i < K * 128) {
    int k = i >> 7, n = i & 127;
    a.dst[y][(size_t)n * K + k] = f2bf(a.src[y][i]);
  }
}

// gru W and U (6 slices each of [128][384]) in one launch; grid (192, 12)
__global__ __launch_bounds__(256) void prep_gru(const float* __restrict__ W,
                                                const float* __restrict__ U,
                                                short* __restrict__ dW,
                                                short* __restrict__ dU) {
  const int y = blockIdx.y;
  const float* s = (y < 6) ? W + (size_t)y * 49152 : U + (size_t)(y - 6) * 49152;
  short* d       = (y < 6) ? dW + (size_t)y * 49152 : dU + (size_t)(y - 6) * 49152;
  int i = blockIdx.x * 256 + threadIdx.x;
  if (i < 49152) {
    int k = i / 384, n = i - k * 384;
    d[(size_t)n * 128 + k] = f2bf(s[i]);
  }
}

// ---------------------------------------------------------------------------
// Projection GEMM, all three tables in one launch via blockIdx.y.
// out[M][128] = bf16(A[M][K]) @ Wt^T + bias; Wt bf16 [128 n][K k].
// Block 256 (4 waves), tile M=32 x N=128, BK=128, per-block K-rotation,
// A-tile register prefetch.
struct ProjA {
  const float* A[3]; const short* Wt[3]; const float* bias[3];
  short* Pb[3]; float* Pf[3]; int M[3]; int K[3];
};

__global__ __launch_bounds__(256) void proj_all(ProjA p) {
  const int y = blockIdx.y;
  const int M = p.M[y];
  const int m0 = blockIdx.x * 32;
  if (m0 >= M) return;                       // inactive tail blocks (cell)
  const int K = p.K[y];
  const float* A    = p.A[y];
  const short* Wt   = p.Wt[y];
  const float* bias = p.bias[y];
  short* Pb         = p.Pb[y];
  float* Pf         = p.Pf[y];

  __shared__ alignas(16) short As[32][136];
  __shared__ alignas(16) short Bs[128][136];
  const int tid  = threadIdx.x;
  const int lane = tid & 63;
  const int w    = tid >> 6;
  const int wc   = w * 32;            // wave col base
  const int quad = lane >> 4;
  const int ln   = lane & 15;

  const int arow = tid >> 3;          // 0..31 (8 threads/row)
  const int akc  = (tid & 7) * 16;    // 16 floats = 64 B contiguous/thread
  const int brow = tid >> 1;          // 0..127 (2 threads/row)
  const int bkc  = (tid & 1) * 64;    // 64 shorts = 128 B/thread

  const int kIters = K >> 7;
  const int krot   = blockIdx.x % kIters;
  const int gr     = m0 + arow;
  const bool aok   = gr < M;
  const float* arp = A + (size_t)gr * K + akc;

  float4 areg[4];
  auto loadA = [&](int k0) {
    if (aok) {
      const float4* ptr = (const float4*)(arp + k0);
      areg[0] = ptr[0]; areg[1] = ptr[1]; areg[2] = ptr[2]; areg[3] = ptr[3];
    } else {
      float4 z = {0.f, 0.f, 0.f, 0.f};
      areg[0] = z; areg[1] = z; areg[2] = z; areg[3] = z;
    }
  };

  f32x4 acc[2][2];
#pragma unroll
  for (int i = 0; i < 2; i++)
#pragma unroll
    for (int j = 0; j < 2; j++) acc[i][j] = (f32x4){0.f, 0.f, 0.f, 0.f};

  loadA(krot << 7);

  for (int it = 0; it < kIters; it++) {
    int ks = krot + it; if (ks >= kIters) ks -= kIters;
    const int k0 = ks << 7;
    {
      bf16x8 v0, v1;
      v0[0]=f2bf(areg[0].x); v0[1]=f2bf(areg[0].y); v0[2]=f2bf(areg[0].z); v0[3]=f2bf(areg[0].w);
      v0[4]=f2bf(areg[1].x); v0[5]=f2bf(areg[1].y); v0[6]=f2bf(areg[1].z); v0[7]=f2bf(areg[1].w);
      v1[0]=f2bf(areg[2].x); v1[1]=f2bf(areg[2].y); v1[2]=f2bf(areg[2].z); v1[3]=f2bf(areg[2].w);
      v1[4]=f2bf(areg[3].x); v1[5]=f2bf(areg[3].y); v1[6]=f2bf(areg[3].z); v1[7]=f2bf(areg[3].w);
      *(bf16x8*)&As[arow][akc]     = v0;
      *(bf16x8*)&As[arow][akc + 8] = v1;
    }
    {
      const short* bp = Wt + (size_t)brow * K + k0 + bkc;
#pragma unroll
      for (int j = 0; j < 8; j++)
        *(bf16x8*)&Bs[brow][bkc + j * 8] = *(const bf16x8*)(bp + j * 8);
    }
    __syncthreads();
    if (it + 1 < kIters) {
      int kn = krot + it + 1; if (kn >= kIters) kn -= kIters;
      loadA(kn << 7);
    }
#pragma unroll
    for (int kt = 0; kt < 4; kt++) {
      bf16x8 af[2], bfr[2];
#pragma unroll
      for (int mi = 0; mi < 2; mi++)
        af[mi] = *(const bf16x8*)&As[mi * 16 + ln][kt * 32 + quad * 8];
#pragma unroll
      for (int nj = 0; nj < 2; nj++)
        bfr[nj] = *(const bf16x8*)&Bs[wc + nj * 16 + ln][kt * 32 + quad * 8];
#pragma unroll
      for (int mi = 0; mi < 2; mi++)
#pragma unroll
        for (int nj = 0; nj < 2; nj++)
          acc[mi][nj] = mfma_bf16(af[mi], bfr[nj], acc[mi][nj]);
    }
    __syncthreads();
  }

#pragma unroll
  for (int mi = 0; mi < 2; mi++)
#pragma unroll
    for (int nj = 0; nj < 2; nj++) {
      const int col = wc + nj * 16 + ln;
      const float bv = bias[col];
#pragma unroll
      for (int r = 0; r < 4; r++) {
        const int row = m0 + mi * 16 + quad * 4 + r;
        if (row < M) {
          const float v = acc[mi][nj][r] + bv;
          if (Pb) Pb[(size_t)row * 128 + col] = f2bf(v);
          if (Pf) Pf[(size_t)row * 128 + col] = v;
        }
      }
    }
}

// ---------------------------------------------------------------------------
// h0 gather: h[b][d] = Pd_f32[ids[b]][d]
__global__ __launch_bounds__(256) void gather_h0(const float* __restrict__ Pd,
                                                 const int* __restrict__ ids,
                                                 float* __restrict__ h) {
  int i = blockIdx.x * 256 + threadIdx.x;   // < 4096*128
  int b = i >> 7, d = i & 127;
  h[i] = Pd[(size_t)ids[b] * 128 + d];
}

// ---------------------------------------------------------------------------
// xw GEMM, all (l,t) in one launch via blockIdx.z (s = s_base + z).
// xwT[slot z][st][row][384] = bf16( P[nbr] @ Wts + gbs )
// grid (640, 3, NS); block tile 64 x 128 of N=384, K=128 single shot.
__global__ __launch_bounds__(256) void xw_all(
    const short* __restrict__ P0, const short* __restrict__ P1,
    const short* __restrict__ P2, const int* __restrict__ n0,
    const int* __restrict__ n1, const int* __restrict__ n2,
    const short* __restrict__ gWt_all, const float* __restrict__ grub_all,
    short* __restrict__ xwT_base, int s_base) {
  const int s  = s_base + blockIdx.z;
  const int ty = s - (s / 3) * 3;
  const short* Pb  = (ty == 0) ? P0 : (ty == 1) ? P1 : P2;
  const int*   nbr = (ty == 0) ? n0 : (ty == 1) ? n1 : n2;
  const short* Wts = gWt_all + (size_t)s * 49152;
  const float* gbs = grub_all + (size_t)s * 384;
  short* xwT = xwT_base + (size_t)blockIdx.z * 40960 * 384;

  __shared__ alignas(16) short As[64][136];
  __shared__ alignas(16) short Bs[128][136];
  const int tid  = threadIdx.x;
  const int lane = tid & 63;
  const int w    = tid >> 6;
  const int wr   = (w >> 1) * 32;
  const int wc   = (w & 1) * 64;
  const int quad = lane >> 4;
  const int ln   = lane & 15;
  const int m0    = blockIdx.x * 64;
  const int nbase = blockIdx.y * 128;

  // stage A: gather 64 rows (128 bf16 each); 4 threads/row x 32 shorts
  {
    const int row = tid >> 2;
    const int kc  = (tid & 3) * 32;
    const int idx = nbr[m0 + row];
    if (idx >= 0) {
      const short* p = Pb + (size_t)idx * 128 + kc;
#pragma unroll
      for (int i = 0; i < 4; i++)
        *(bf16x8*)&As[row][kc + i * 8] = *(const bf16x8*)(p + i * 8);
    } else {
      bf16x8 zv;
#pragma unroll
      for (int i = 0; i < 8; i++) zv[i] = 0;
#pragma unroll
      for (int i = 0; i < 4; i++) *(bf16x8*)&As[row][kc + i * 8] = zv;
    }
  }
  // stage B: 128 rows x 128 k from Wts[nbase+n][k]; 2 threads/row x 64 shorts
  {
    const int n  = tid >> 1;
    const int kc = (tid & 1) * 64;
    const short* p = Wts + (size_t)(nbase + n) * 128 + kc;
#pragma unroll
    for (int i = 0; i < 8; i++)
      *(bf16x8*)&Bs[n][kc + i * 8] = *(const bf16x8*)(p + i * 8);
  }
  __syncthreads();

  f32x4 acc[2][4];
#pragma unroll
  for (int i = 0; i < 2; i++)
#pragma unroll
    for (int j = 0; j < 4; j++) acc[i][j] = (f32x4){0.f, 0.f, 0.f, 0.f};

#pragma unroll
  for (int kt = 0; kt < 4; kt++) {
    bf16x8 af[2], bfr[4];
#pragma unroll
    for (int mi = 0; mi < 2; mi++)
      af[mi] = *(const bf16x8*)&As[wr + mi * 16 + ln][kt * 32 + quad * 8];
#pragma unroll
    for (int nj = 0; nj < 4; nj++)
      bfr[nj] = *(const bf16x8*)&Bs[wc + nj * 16 + ln][kt * 32 + quad * 8];
#pragma unroll
    for (int mi = 0; mi < 2; mi++)
#pragma unroll
      for (int nj = 0; nj < 4; nj++)
        acc[mi][nj] = mfma_bf16(af[mi], bfr[nj], acc[mi][nj]);
  }

#pragma unroll
  for (int mi = 0; mi < 2; mi++)
#pragma unroll
    for (int nj = 0; nj < 4; nj++) {
      const int col = wc + nj * 16 + ln;
      const float bv = gbs[nbase + col];
#pragma unroll
      for (int r = 0; r < 4; r++) {
        const int rt   = m0 + wr + mi * 16 + quad * 4 + r;  // = row*10 + st
        const int grow = rt / 10;
        const int st   = rt - grow * 10;
        xwT[((size_t)st * 4096 + grow) * 384 + nbase + col] =
            f2bf(acc[mi][nj][r] + bv);
      }
    }
}

// ---------------------------------------------------------------------------
// Fused GRU scan over T=10, all (l,t) in one launch via blockIdx.y.
// Block = 16 batch rows, 4 waves. xw staged per-step through LDS
// (contiguous 12 KB loads from the step-major xwT layout); U in registers;
// h via LDS (bf16). grid (256, NS).
__global__ __launch_bounds__(256) void scan_all(
    const short* __restrict__ xwT_base, const short* __restrict__ Ut_base,
    const int* __restrict__ n0, const int* __restrict__ n1,
    const int* __restrict__ n2, float* __restrict__ out_base, int s_base) {
  const int sz = blockIdx.y;
  const int s  = s_base + sz;
  const int ty = s - (s / 3) * 3;
  const short* xwT = xwT_base + (size_t)sz * 40960 * 384;
  const short* Utz = Ut_base + (size_t)s * 49152;
  const int*   nbr = (ty == 0) ? n0 : (ty == 1) ? n1 : n2;
  float* outp = out_base + (size_t)sz * 4096 * 128;

  __shared__ alignas(16) short hs[16][128];
  __shared__ alignas(16) short xls[16][392];
  __shared__ float mask_s[16][10];
  __shared__ float cinv[16];

  const int tid  = threadIdx.x;
  const int lane = tid & 63;
  const int w    = tid >> 6;
  const int nb   = w * 32;
  const int quad = lane >> 4;
  const int ln   = lane & 15;
  const int r0   = blockIdx.x * 16;

  if (tid < 160) {
    int i = tid / 10, tt = tid % 10;
    mask_s[i][tt] = (nbr[(r0 + i) * 10 + tt] >= 0) ? 1.f : 0.f;
  }
  {
    short* hf = &hs[0][0];
    for (int i = tid; i < 16 * 128; i += 256) hf[i] = 0;
  }
  __syncthreads();
  if (tid < 16) {
    float sm = 0.f;
    for (int tt = 0; tt < 10; tt++) sm += mask_s[tid][tt];
    cinv[tid] = 1.f / fmaxf(sm, 1.f);
  }

  bf16x8 u[3][2][4];
#pragma unroll
  for (int g = 0; g < 3; g++)
#pragma unroll
    for (int jj = 0; jj < 2; jj++)
#pragma unroll
      for (int kt = 0; kt < 4; kt++)
        u[g][jj][kt] = *(const bf16x8*)(Utz +
            (size_t)(g * 128 + nb + jj * 16 + ln) * 128 + kt * 32 + quad * 8);

  // xw stage addressing (16 rows x 384 shorts = 256 threads x 24 shorts)
  int srow[3], scol[3];
#pragma unroll
  for (int j = 0; j < 3; j++) {
    const int o = tid * 24 + j * 8;
    srow[j] = o / 384;
    scol[j] = o - srow[j] * 384;
  }

  float hreg[2][4], oacc[2][4];
#pragma unroll
  for (int jj = 0; jj < 2; jj++)
#pragma unroll
    for (int r = 0; r < 4; r++) { hreg[jj][r] = 0.f; oacc[jj][r] = 0.f; }

  __syncthreads();

  for (int st = 0; st < 10; st++) {
    // a-frags from hs (published by previous step's final barrier)
    bf16x8 a[4];
#pragma unroll
    for (int kt = 0; kt < 4; kt++)
      a[kt] = *(const bf16x8*)&hs[ln][kt * 32 + quad * 8];

    // issue this step's xw loads (16 rows contiguous in step-major layout)
    const short* src = xwT + ((size_t)st * 4096 + r0) * 384;
    bf16x8 xrg[3];
#pragma unroll
    for (int j = 0; j < 3; j++)
      xrg[j] = *(const bf16x8*)(src + tid * 24 + j * 8);

    // h @ U while loads are in flight
    f32x4 hu[3][2];
#pragma unroll
    for (int g = 0; g < 3; g++)
#pragma unroll
      for (int jj = 0; jj < 2; jj++) hu[g][jj] = (f32x4){0.f, 0.f, 0.f, 0.f};
#pragma unroll
    for (int kt = 0; kt < 4; kt++)
#pragma unroll
      for (int g = 0; g < 3; g++)
#pragma unroll
        for (int jj = 0; jj < 2; jj++)
          hu[g][jj] = mfma_bf16(a[kt], u[g][jj][kt], hu[g][jj]);

#pragma unroll
    for (int j = 0; j < 3; j++)
      *(bf16x8*)&xls[srow[j]][scol[j]] = xrg[j];
    __syncthreads();   // xls staged; all hs reads done

#pragma unroll
    for (int jj = 0; jj < 2; jj++) {
      const int col = nb + jj * 16 + ln;
#pragma unroll
      for (int r = 0; r < 4; r++) {
        const int row = quad * 4 + r;
        const float xz = b2f(xls[row][col]);
        const float xr = b2f(xls[row][col + 128]);
        const float xn = b2f(xls[row][col + 256]);
        const float zg = 1.f / (1.f + __expf(-(xz + hu[0][jj][r])));
        const float rg = 1.f / (1.f + __expf(-(xr + hu[1][jj][r])));
        const float pn = xn + rg * hu[2][jj][r];
        const float e2 = __expf(2.f * pn);
        const float n  = (e2 - 1.f) / (e2 + 1.f);
        const float hn = (1.f - zg) * n + zg * hreg[jj][r];
        hreg[jj][r] = hn;
        oacc[jj][r] += hn * mask_s[row][st];
        hs[row][col] = f2bf(hn);
      }
    }
    __syncthreads();   // hs published; xls free for next step
  }

#pragma unroll
  for (int jj = 0; jj < 2; jj++)
#pragma unroll
    for (int r = 0; r < 4; r++) {
      const int row = quad * 4 + r;
      outp[(size_t)(r0 + row) * 128 + nb + jj * 16 + ln] =
          oacc[jj][r] * cinv[row];
    }
}

// ---------------------------------------------------------------------------
// Attention: one wave per batch row; softmax over {h, c0, c1, c2}.
__global__ __launch_bounds__(256) void attn_kernel(
    const float* __restrict__ hin, const float* __restrict__ cand,
    const float* __restrict__ att, float* __restrict__ hout) {
  const int tid  = threadIdx.x;
  const int lane = tid & 63;
  const int w    = tid >> 6;
  const int gb   = blockIdx.x * 4 + w;

  const float ah0 = att[lane],       ah1 = att[lane + 64];
  const float ac0 = att[128 + lane], ac1 = att[192 + lane];

  float c0[4], c1[4];
  c0[0] = hin[(size_t)gb * 128 + lane];
  c1[0] = hin[(size_t)gb * 128 + 64 + lane];
#pragma unroll
  for (int k = 1; k < 4; k++) {
    const float* p = cand + (size_t)(k - 1) * 4096 * 128 + (size_t)gb * 128;
    c0[k] = p[lane]; c1[k] = p[64 + lane];
  }

  float sh = ah0 * c0[0] + ah1 * c1[0];
#pragma unroll
  for (int m = 1; m < 64; m <<= 1) sh += __shfl_xor(sh, m);

  float e[4];
#pragma unroll
  for (int k = 0; k < 4; k++) {
    float sv = ac0 * c0[k] + ac1 * c1[k];
#pragma unroll
    for (int m = 1; m < 64; m <<= 1) sv += __shfl_xor(sv, m);
    sv += sh;
    e[k] = (sv > 0.f) ? sv : 0.01f * sv;
  }
  const float mx = fmaxf(fmaxf(e[0], e[1]), fmaxf(e[2], e[3]));
  float wk[4], wsum = 0.f;
#pragma unroll
  for (int k = 0; k < 4; k++) { wk[k] = __expf(e[k] - mx); wsum += wk[k]; }
  const float inv = 1.f / wsum;
  float o0 = 0.f, o1 = 0.f;
#pragma unroll
  for (int k = 0; k < 4; k++) { o0 += wk[k] * c0[k]; o1 += wk[k] * c1[k]; }
  hout[(size_t)gb * 128 + lane]      = o0 * inv;
  hout[(size_t)gb * 128 + 64 + lane] = o1 * inv;
}

// ---------------------------------------------------------------------------
extern "C" void kernel_launch(void* const* d_in, const int* in_sizes, int n_in,
                              void* d_out, int out_size, void* d_ws, size_t ws_size,
                              hipStream_t stream) {
  const float* drug = (const float*)d_in[0];
  const float* gene = (const float*)d_in[1];
  const float* cell = (const float*)d_in[2];
  const float* Wd   = (const float*)d_in[3];
  const float* bd   = (const float*)d_in[4];
  const float* Wg   = (const float*)d_in[5];
  const float* bg   = (const float*)d_in[6];
  const float* Wc   = (const float*)d_in[7];
  const float* bc   = (const float*)d_in[8];
  const float* gruW = (const float*)d_in[9];
  const float* gruU = (const float*)d_in[10];
  const float* grub = (const float*)d_in[11];
  const float* att  = (const float*)d_in[12];
  const int* ids    = (const int*)d_in[13];
  const int* nbr[3] = {(const int*)d_in[14], (const int*)d_in[15],
                       (const int*)d_in[16]};

  const size_t XW_SLOT   = (size_t)40960 * 384;       // shorts
  const size_t CAND_SLOT = (size_t)4096 * 128;        // floats

  // merged path needs ~228.6 MB; fallback ~66 MB
  const size_t need_big =
      (size_t)20000 * 128 * 4 + (size_t)20000 * 128 * 2 +
      (size_t)20000 * 128 * 2 + (size_t)10000 * 128 * 2 +
      (size_t)4096 * 128 * 4 + 6 * CAND_SLOT * 4 + 6 * XW_SLOT * 2 +
      (size_t)2048 * 128 * 2 + (size_t)1024 * 128 * 2 + (size_t)512 * 128 * 2 +
      2 * (size_t)6 * 384 * 128 * 2 + 16384 /*align slack*/;
  const bool big = ws_size >= need_big;

  char* ws = (char*)d_ws;
  auto alloc = [&](size_t bytes) {
    void* p = ws; ws += (bytes + 255) & ~(size_t)255; return p;
  };
  float* Pdf  = (float*)alloc((size_t)20000 * 128 * 4);   // drug proj, f32
  short* Pdb  = (short*)alloc((size_t)20000 * 128 * 2);   // drug proj, bf16
  short* Pgb  = (short*)alloc((size_t)20000 * 128 * 2);   // gene proj, bf16
  short* Pcb  = (short*)alloc((size_t)10000 * 128 * 2);   // cell proj, bf16
  float* h    = (float*)alloc((size_t)4096 * 128 * 4);
  float* cand = (float*)alloc((big ? 6 : 3) * CAND_SLOT * 4);
  short* xwb  = (short*)alloc((big ? 6 : 1) * XW_SLOT * 2); // [10][4096][384]/slot
  short* Wdt  = (short*)alloc((size_t)2048 * 128 * 2);
  short* Wgt  = (short*)alloc((size_t)1024 * 128 * 2);
  short* Wct  = (short*)alloc((size_t)512 * 128 * 2);
  short* gWt  = (short*)alloc((size_t)6 * 384 * 128 * 2);
  short* Ut   = (short*)alloc((size_t)6 * 384 * 128 * 2);

  // weight prep (bf16, B-operand [N][K] layout): 2 launches
  {
    PrepW pw;
    pw.src[0] = Wd;  pw.dst[0] = Wdt; pw.K[0] = 2048;
    pw.src[1] = Wg;  pw.dst[1] = Wgt; pw.K[1] = 1024;
    pw.src[2] = Wc;  pw.dst[2] = Wct; pw.K[2] = 512;
    prep_w<<<dim3(1024, 3), 256, 0, stream>>>(pw);
  }
  prep_gru<<<dim3(192, 12), 256, 0, stream>>>(gruW, gruU, gWt, Ut);

  // projections: one launch (drug writes f32 for h0/attn AND bf16 for xw)
  {
    ProjA pa;
    pa.A[0] = drug; pa.Wt[0] = Wdt; pa.bias[0] = bd;
    pa.Pb[0] = Pdb; pa.Pf[0] = Pdf; pa.M[0] = 20000; pa.K[0] = 2048;
    pa.A[1] = gene; pa.Wt[1] = Wgt; pa.bias[1] = bg;
    pa.Pb[1] = Pgb; pa.Pf[1] = nullptr; pa.M[1] = 20000; pa.K[1] = 1024;
    pa.A[2] = cell; pa.Wt[2] = Wct; pa.bias[2] = bc;
    pa.Pb[2] = Pcb; pa.Pf[2] = nullptr; pa.M[2] = 10000; pa.K[2] = 512;
    proj_all<<<dim3(625, 3), 256, 0, stream>>>(pa);
  }
  gather_h0<<<2048, 256, 0, stream>>>(Pdf, ids, h);

  if (big) {
    // all 6 xw GEMMs in one launch, all 6 GRU scans in one launch
    xw_all<<<dim3(640, 3, 6), 256, 0, stream>>>(
        Pdb, Pgb, Pcb, nbr[0], nbr[1], nbr[2], gWt, grub, xwb, 0);
    scan_all<<<dim3(256, 6), 256, 0, stream>>>(
        xwb, Ut, nbr[0], nbr[1], nbr[2], cand, 0);
    attn_kernel<<<1024, 256, 0, stream>>>(h, cand, att, h);
    attn_kernel<<<1024, 256, 0, stream>>>(
        h, cand + 3 * CAND_SLOT, att + 256, (float*)d_out);
  } else {
    // sequential fallback (small workspace): 1-slot xwb, 3-slot cand
    for (int l = 0; l < 2; l++) {
      for (int t = 0; t < 3; t++) {
        const int s = l * 3 + t;
        xw_all<<<dim3(640, 3, 1), 256, 0, stream>>>(
            Pdb, Pgb, Pcb, nbr[0], nbr[1], nbr[2], gWt, grub, xwb, s);
        scan_all<<<dim3(256, 1), 256, 0, stream>>>(
            xwb, Ut, nbr[0], nbr[1], nbr[2], cand + (size_t)t * CAND_SLOT, s);
      }
      attn_kernel<<<1024, 256, 0, stream>>>(
          h, cand, att + l * 256, (l == 1) ? (float*)d_out : h);
    }
  }
}